// Round 1
// baseline (169.503 us; speedup 1.0000x reference)
//
#include <hip/hip_runtime.h>

// ---------------- constants ----------------
// B=16, CIN=256, COUT=256, H=W=64, K=3, SDIM=128
// ws layout (bytes):
//   xpad  bf16 [16][66][66][256] : 0          .. 35,684,352
//   wmod  bf16 [16][9][256][256] : 35,684,352 .. 54,558,720
//   s     f32  [16][256]         : 54,558,720 .. 54,575,104
//   demod f32  [16][256]         : 54,575,104 .. 54,591,488

#define XPAD_BYTES 35684352
#define WMOD_OFF   35684352
#define S_OFF      54558720
#define DEMOD_OFF  54575104

typedef __attribute__((ext_vector_type(8))) short bf16x8;
typedef __attribute__((ext_vector_type(4))) float f32x4;

#define GLOAD_LDS16(g, l)                                                        \
  __builtin_amdgcn_global_load_lds(                                              \
      (const __attribute__((address_space(1))) void*)(g),                        \
      (__attribute__((address_space(3))) void*)(l), 16, 0, 0)

__device__ __forceinline__ unsigned short f2bf(float f) {
  unsigned int u = __builtin_bit_cast(unsigned int, f);
  u += 0x7FFFu + ((u >> 16) & 1u);  // round-to-nearest-even
  return (unsigned short)(u >> 16);
}

// ---------------- kernel 1: style s[b][i] ----------------
__global__ void style_k(const float* __restrict__ c_trg,
                        const float* __restrict__ style_w,
                        const float* __restrict__ style_b,
                        float* __restrict__ s) {
  const int b = blockIdx.x;
  const int i = threadIdx.x;  // 0..255
  const float* ct = c_trg + b * 128;
  const float* sw = style_w + i * 128;
  float acc = 0.f;
#pragma unroll 4
  for (int d = 0; d < 128; ++d) acc += ct[d] * sw[d];
  s[b * 256 + i] = acc * 0.08838834764831845f + style_b[i];  // 1/sqrt(128)
}

// ---------------- kernel 2: modulated weights (bf16) + demod ----------------
// block = (b, cout); thread = cin. wmod[b][tap][cout][cin] = conv_scale*w*s
__global__ void modw_k(const float* __restrict__ weight,
                       const float* __restrict__ s,
                       short* __restrict__ wmod,
                       float* __restrict__ demod) {
  const int bid = blockIdx.x;       // b*256 + co
  const int b = bid >> 8, co = bid & 255;
  const int ci = threadIdx.x;
  const float sv = s[b * 256 + ci] * 0.020833333333333332f;  // 1/sqrt(2304)
  const float* wsrc = weight + (co * 256 + ci) * 9;
  float ss = 0.f;
  short* dst = wmod + (b * 9) * 65536 + co * 256 + ci;
#pragma unroll
  for (int t = 0; t < 9; ++t) {
    float v = wsrc[t] * sv;
    ss += v * v;
    dst[t * 65536] = (short)f2bf(v);
  }
#pragma unroll
  for (int o = 32; o; o >>= 1) ss += __shfl_down(ss, o);
  __shared__ float red[4];
  if ((ci & 63) == 0) red[ci >> 6] = ss;
  __syncthreads();
  if (ci == 0) {
    float tot = red[0] + red[1] + red[2] + red[3];
    demod[bid] = rsqrtf(tot + 1e-8f);
  }
}

// ---------------- kernel 3: x fp32 NCHW -> bf16 padded NHWC ----------------
// block = (b, h, ct): transpose 64c x 64w tile via LDS.
__global__ void xpose_k(const float* __restrict__ x, short* __restrict__ xpad) {
  __shared__ float tile[64][65];
  const int bid = blockIdx.x;  // b*256 + h*4 + ct
  const int ct = bid & 3;
  const int h = (bid >> 2) & 63;
  const int b = bid >> 8;
  const int tid = threadIdx.x;
  const int w = tid & 63, cl = tid >> 6;
  const float* src = x + ((b * 256 + ct * 64) * 64 + h) * 64;
#pragma unroll
  for (int i = 0; i < 16; ++i) {
    int c = i * 4 + cl;
    tile[c][w] = src[c * 4096 + w];
  }
  __syncthreads();
  short* dst = xpad + ((b * 66 + h + 1) * 66 + 1) * 256 + ct * 64;
#pragma unroll
  for (int i = 0; i < 8; ++i) {
    int idx = i * 256 + tid;
    int w2 = idx >> 5;   // 0..63
    int cp = idx & 31;   // c-pair
    unsigned int u = (unsigned int)f2bf(tile[cp * 2][w2]) |
                     ((unsigned int)f2bf(tile[cp * 2 + 1][w2]) << 16);
    *(unsigned int*)(dst + w2 * 256 + cp * 2) = u;
  }
}

// ---------------- kernel 4: implicit-GEMM conv, 128x128 tile, BK=64 ----------------
// grid: 16 samples * 2 cout-tiles * 32 pixel-tiles(2 rows). 256 thr = 4 waves.
__global__ __launch_bounds__(256) void conv_k(const short* __restrict__ xpad,
                                              const short* __restrict__ wmod,
                                              const float* __restrict__ demod,
                                              float* __restrict__ out) {
  __shared__ __align__(16) short As[128 * 64];  // [cout 128][cin 64]
  __shared__ __align__(16) short Bs[128 * 64];  // [pixel 128][cin 64]

  const int tid = threadIdx.x;
  const int lane = tid & 63;
  const int wid = tid >> 6;
  const int wr = wid >> 1, wc = wid & 1;

  const int bid = blockIdx.x;
  const int b = bid >> 6;
  const int rem = bid & 63;
  const int cout0 = (rem & 1) * 128;
  const int r0 = (rem >> 1) * 2;  // first output row of this tile

  // staging address precompute: chunk q = i*256+tid; row=q>>3; 16B col = (tid&7)*16
  const int t3 = tid >> 3;
  const int c16 = (tid & 7) * 16;
  int aRow[4], bPix[4];
#pragma unroll
  for (int i = 0; i < 4; ++i) {
    aRow[i] = (cout0 + i * 32 + t3) * 512 + c16;  // bytes into wmod[b][tap]
    int n = i * 32 + t3;                          // pixel 0..127
    int h = r0 + (n >> 6), w = n & 63;
    bPix[i] = ((b * 66 + h) * 66 + w) * 512 + c16;  // bytes into xpad
  }

  const char* wB = (const char*)wmod;
  const char* xB = (const char*)xpad;

  f32x4 acc[4][4] = {};

  const char* Ard = (const char*)As + (wr * 64 + (lane & 15)) * 128 + (lane >> 4) * 16;
  const char* Brd = (const char*)Bs + (wc * 64 + (lane & 15)) * 128 + (lane >> 4) * 16;

  for (int tap = 0; tap < 9; ++tap) {
    const int aTap = (b * 9 + tap) * 131072;                 // bytes
    const int bTap = ((tap / 3) * 66 + (tap % 3)) * 512;     // row/col shift
#pragma unroll 1
    for (int cc = 0; cc < 4; ++cc) {
      const int ccB = cc * 128;
#pragma unroll
      for (int i = 0; i < 4; ++i) {
        GLOAD_LDS16(wB + aTap + aRow[i] + ccB, (char*)As + (i * 4 + wid) * 1024);
        GLOAD_LDS16(xB + bTap + bPix[i] + ccB, (char*)Bs + (i * 4 + wid) * 1024);
      }
      __syncthreads();
#pragma unroll
      for (int ks = 0; ks < 2; ++ks) {
        bf16x8 af[4], bfr[4];
#pragma unroll
        for (int m = 0; m < 4; ++m) af[m] = *(const bf16x8*)(Ard + m * 2048 + ks * 64);
#pragma unroll
        for (int n = 0; n < 4; ++n) bfr[n] = *(const bf16x8*)(Brd + n * 2048 + ks * 64);
#pragma unroll
        for (int m = 0; m < 4; ++m)
#pragma unroll
          for (int n = 0; n < 4; ++n)
            acc[m][n] = __builtin_amdgcn_mfma_f32_16x16x32_bf16(af[m], bfr[n], acc[m][n], 0, 0, 0);
      }
      __syncthreads();
    }
  }

  // epilogue: scale by demod[b][cout], store fp32 NCHW
  const int pc = lane & 15;
  const int rOff = (lane >> 4) * 4;
#pragma unroll
  for (int m = 0; m < 4; ++m) {
#pragma unroll
    for (int r = 0; r < 4; ++r) {
      const int co = cout0 + wr * 64 + m * 16 + rOff + r;
      const float dm = demod[(b << 8) + co];
      float* orow = out + (((b << 8) + co) << 12);
#pragma unroll
      for (int n = 0; n < 4; ++n) {
        const int pix = wc * 64 + n * 16 + pc;
        const int h = r0 + (pix >> 6), w = pix & 63;
        orow[(h << 6) + w] = acc[m][n][r] * dm;
      }
    }
  }
}

// ---------------- launcher ----------------
extern "C" void kernel_launch(void* const* d_in, const int* in_sizes, int n_in,
                              void* d_out, int out_size, void* d_ws, size_t ws_size,
                              hipStream_t stream) {
  const float* x       = (const float*)d_in[0];
  // d_in[1] = c_src (unused by reference)
  const float* c_trg   = (const float*)d_in[2];
  const float* style_w = (const float*)d_in[3];
  const float* style_b = (const float*)d_in[4];
  const float* weight  = (const float*)d_in[5];
  float* out = (float*)d_out;

  char* ws = (char*)d_ws;
  short* xpad  = (short*)(ws);
  short* wmod  = (short*)(ws + WMOD_OFF);
  float* s     = (float*)(ws + S_OFF);
  float* demod = (float*)(ws + DEMOD_OFF);

  hipMemsetAsync(xpad, 0, XPAD_BYTES, stream);          // zero borders
  style_k<<<16, 256, 0, stream>>>(c_trg, style_w, style_b, s);
  modw_k<<<4096, 256, 0, stream>>>(weight, s, wmod, demod);
  xpose_k<<<4096, 256, 0, stream>>>(x, xpad);
  conv_k<<<1024, 256, 0, stream>>>(xpad, wmod, demod, out);
}

// Round 2
// 142.151 us; speedup vs baseline: 1.1924x; 1.1924x over previous
//
#include <hip/hip_runtime.h>

// ---------------- constants ----------------
// B=16, CIN=256, COUT=256, H=W=64, K=3, SDIM=128
// ws layout (bytes):
//   xpad  bf16 [16][66][66][256] : 0          .. 35,684,352
//   wmod  bf16 [16][9][256][256] : 35,684,352 .. 54,558,720
//   s     f32  [16][256]         : 54,558,720 .. 54,575,104
//   demod f32  [16][256]         : 54,575,104 .. 54,591,488

#define XPAD_BYTES 35684352
#define WMOD_OFF   35684352
#define S_OFF      54558720
#define DEMOD_OFF  54575104

typedef __attribute__((ext_vector_type(8))) short bf16x8;
typedef __attribute__((ext_vector_type(4))) float f32x4;

#define GLOAD_LDS16(g, l)                                                        \
  __builtin_amdgcn_global_load_lds(                                              \
      (const __attribute__((address_space(1))) void*)(g),                        \
      (__attribute__((address_space(3))) void*)(l), 16, 0, 0)

__device__ __forceinline__ unsigned short f2bf(float f) {
  unsigned int u = __builtin_bit_cast(unsigned int, f);
  u += 0x7FFFu + ((u >> 16) & 1u);  // round-to-nearest-even
  return (unsigned short)(u >> 16);
}

// ---------------- kernel 1: style s[b][i] ----------------
__global__ void style_k(const float* __restrict__ c_trg,
                        const float* __restrict__ style_w,
                        const float* __restrict__ style_b,
                        float* __restrict__ s) {
  const int b = blockIdx.x;
  const int i = threadIdx.x;  // 0..255
  const float* ct = c_trg + b * 128;
  const float* sw = style_w + i * 128;
  float acc = 0.f;
#pragma unroll 4
  for (int d = 0; d < 128; ++d) acc += ct[d] * sw[d];
  s[b * 256 + i] = acc * 0.08838834764831845f + style_b[i];  // 1/sqrt(128)
}

// ---------------- kernel 2: modulated weights (bf16) + demod ----------------
// block = (b, cout); thread = cin. wmod[b][tap][cout][cin] = conv_scale*w*s
__global__ void modw_k(const float* __restrict__ weight,
                       const float* __restrict__ s,
                       short* __restrict__ wmod,
                       float* __restrict__ demod) {
  const int bid = blockIdx.x;       // b*256 + co
  const int b = bid >> 8, co = bid & 255;
  const int ci = threadIdx.x;
  const float sv = s[b * 256 + ci] * 0.020833333333333332f;  // 1/sqrt(2304)
  const float* wsrc = weight + (co * 256 + ci) * 9;
  float ss = 0.f;
  short* dst = wmod + (b * 9) * 65536 + co * 256 + ci;
#pragma unroll
  for (int t = 0; t < 9; ++t) {
    float v = wsrc[t] * sv;
    ss += v * v;
    dst[t * 65536] = (short)f2bf(v);
  }
#pragma unroll
  for (int o = 32; o; o >>= 1) ss += __shfl_down(ss, o);
  __shared__ float red[4];
  if ((ci & 63) == 0) red[ci >> 6] = ss;
  __syncthreads();
  if (ci == 0) {
    float tot = red[0] + red[1] + red[2] + red[3];
    demod[bid] = rsqrtf(tot + 1e-8f);
  }
}

// ---------------- kernel 3: x fp32 NCHW -> bf16 padded NHWC ----------------
// block = (b, h, ct): transpose 64c x 64w tile via LDS.
__global__ void xpose_k(const float* __restrict__ x, short* __restrict__ xpad) {
  __shared__ float tile[64][65];
  const int bid = blockIdx.x;  // b*256 + h*4 + ct
  const int ct = bid & 3;
  const int h = (bid >> 2) & 63;
  const int b = bid >> 8;
  const int tid = threadIdx.x;
  const int w = tid & 63, cl = tid >> 6;
  const float* src = x + ((b * 256 + ct * 64) * 64 + h) * 64;
#pragma unroll
  for (int i = 0; i < 16; ++i) {
    int c = i * 4 + cl;
    tile[c][w] = src[c * 4096 + w];
  }
  __syncthreads();
  short* dst = xpad + ((b * 66 + h + 1) * 66 + 1) * 256 + ct * 64;
#pragma unroll
  for (int i = 0; i < 8; ++i) {
    int idx = i * 256 + tid;
    int w2 = idx >> 5;   // 0..63
    int cp = idx & 31;   // c-pair
    unsigned int u = (unsigned int)f2bf(tile[cp * 2][w2]) |
                     ((unsigned int)f2bf(tile[cp * 2 + 1][w2]) << 16);
    *(unsigned int*)(dst + w2 * 256 + cp * 2) = u;
  }
}

// ---------------- kernel 4: implicit-GEMM conv, 128x128 tile, BK=64 ----------------
// grid: 16 samples * 2 cout-tiles * 32 pixel-tiles(2 rows). 256 thr = 4 waves.
// T1: bijective XCD swizzle -> each XCD owns 2 samples (L2-resident working set).
// T2: LDS XOR-swizzle (byte ^= (row&7)<<4) via pre-swizzled GLOBAL source
//     (global_load_lds writes linearly), swizzled ds_read addresses.
__global__ __launch_bounds__(256) void conv_k(const short* __restrict__ xpad,
                                              const short* __restrict__ wmod,
                                              const float* __restrict__ demod,
                                              float* __restrict__ out) {
  __shared__ __align__(16) short As[128 * 64];  // [cout 128][cin 64]
  __shared__ __align__(16) short Bs[128 * 64];  // [pixel 128][cin 64]

  const int tid = threadIdx.x;
  const int lane = tid & 63;
  const int wid = tid >> 6;
  const int wr = wid >> 1, wc = wid & 1;

  // T1: XCD-aware swizzle. grid=1024, 1024%8==0 -> simple bijective form.
  const int orig = blockIdx.x;
  const int bid = (orig & 7) * 128 + (orig >> 3);

  const int b = bid >> 6;
  const int rem = bid & 63;
  const int cout0 = (rem & 1) * 128;
  const int r0 = (rem >> 1) * 2;  // first output row of this tile

  // staging address precompute: chunk q = i*256+tid; row=q>>3; 16B col = (tid&7)*16
  const int t3 = tid >> 3;
  const int c16 = (tid & 7) * 16;
  // T2 write side: LDS slot (row, c16) must receive global (row, c16 ^ ((row&7)<<4)).
  const int swzc = c16 ^ ((t3 & 7) << 4);
  int aRow[4], bPix[4];
#pragma unroll
  for (int i = 0; i < 4; ++i) {
    aRow[i] = (cout0 + i * 32 + t3) * 512 + swzc;  // bytes into wmod[b][tap]
    int n = i * 32 + t3;                           // pixel 0..127
    int h = r0 + (n >> 6), w = n & 63;
    bPix[i] = ((b * 66 + h) * 66 + w) * 512 + swzc;  // bytes into xpad
  }

  const char* wB = (const char*)wmod;
  const char* xB = (const char*)xpad;

  f32x4 acc[4][4] = {};

  // T2 read side: col_read = col ^ ((row&7)<<4); row&7 == lane&7 for all m,ks.
  // Split XOR term: bits 4-5 fold into base, bit 6 folds into the ks offset.
  const int xall = (lane & 7) << 4;
  const int xl = xall & 0x30;
  const int xh = xall & 0x40;
  const int colR = (((lane >> 4) << 4) ^ xl);
  const int ksOff0 = xh;
  const int ksOff1 = 64 ^ xh;
  const char* Ard = (const char*)As + (wr * 64 + (lane & 15)) * 128 + colR;
  const char* Brd = (const char*)Bs + (wc * 64 + (lane & 15)) * 128 + colR;

  for (int tap = 0; tap < 9; ++tap) {
    const int aTap = (b * 9 + tap) * 131072;                 // bytes
    const int bTap = ((tap / 3) * 66 + (tap % 3)) * 512;     // row/col shift
#pragma unroll 1
    for (int cc = 0; cc < 4; ++cc) {
      const int ccB = cc * 128;
#pragma unroll
      for (int i = 0; i < 4; ++i) {
        GLOAD_LDS16(wB + aTap + aRow[i] + ccB, (char*)As + (i * 4 + wid) * 1024);
        GLOAD_LDS16(xB + bTap + bPix[i] + ccB, (char*)Bs + (i * 4 + wid) * 1024);
      }
      __syncthreads();
#pragma unroll
      for (int ks = 0; ks < 2; ++ks) {
        const int ko = ks ? ksOff1 : ksOff0;
        bf16x8 af[4], bfr[4];
#pragma unroll
        for (int m = 0; m < 4; ++m) af[m] = *(const bf16x8*)(Ard + m * 2048 + ko);
#pragma unroll
        for (int n = 0; n < 4; ++n) bfr[n] = *(const bf16x8*)(Brd + n * 2048 + ko);
#pragma unroll
        for (int m = 0; m < 4; ++m)
#pragma unroll
          for (int n = 0; n < 4; ++n)
            acc[m][n] = __builtin_amdgcn_mfma_f32_16x16x32_bf16(af[m], bfr[n], acc[m][n], 0, 0, 0);
      }
      __syncthreads();
    }
  }

  // epilogue: scale by demod[b][cout], store fp32 NCHW
  const int pc = lane & 15;
  const int rOff = (lane >> 4) * 4;
#pragma unroll
  for (int m = 0; m < 4; ++m) {
#pragma unroll
    for (int r = 0; r < 4; ++r) {
      const int co = cout0 + wr * 64 + m * 16 + rOff + r;
      const float dm = demod[(b << 8) + co];
      float* orow = out + (((b << 8) + co) << 12);
#pragma unroll
      for (int n = 0; n < 4; ++n) {
        const int pix = wc * 64 + n * 16 + pc;
        const int h = r0 + (pix >> 6), w = pix & 63;
        orow[(h << 6) + w] = acc[m][n][r] * dm;
      }
    }
  }
}

// ---------------- launcher ----------------
extern "C" void kernel_launch(void* const* d_in, const int* in_sizes, int n_in,
                              void* d_out, int out_size, void* d_ws, size_t ws_size,
                              hipStream_t stream) {
  const float* x       = (const float*)d_in[0];
  // d_in[1] = c_src (unused by reference)
  const float* c_trg   = (const float*)d_in[2];
  const float* style_w = (const float*)d_in[3];
  const float* style_b = (const float*)d_in[4];
  const float* weight  = (const float*)d_in[5];
  float* out = (float*)d_out;

  char* ws = (char*)d_ws;
  short* xpad  = (short*)(ws);
  short* wmod  = (short*)(ws + WMOD_OFF);
  float* s     = (float*)(ws + S_OFF);
  float* demod = (float*)(ws + DEMOD_OFF);

  hipMemsetAsync(xpad, 0, XPAD_BYTES, stream);          // zero borders
  style_k<<<16, 256, 0, stream>>>(c_trg, style_w, style_b, s);
  modw_k<<<4096, 256, 0, stream>>>(weight, s, wmod, demod);
  xpose_k<<<4096, 256, 0, stream>>>(x, xpad);
  conv_k<<<1024, 256, 0, stream>>>(xpad, wmod, demod, out);
}

// Round 3
// 121.095 us; speedup vs baseline: 1.3997x; 1.1739x over previous
//
#include <hip/hip_runtime.h>

// ---------------- constants ----------------
// B=16, CIN=256, COUT=256, H=W=64, K=3, SDIM=128
// Separable reformulation:
//   out[b,co,p] = demod[b,co] * sum_{t,ci} wsh[t,co,ci] * y[b,ci,p+shift(t)]
//   wsh = conv_scale * w  (batch-independent!),  y = s[b,ci] * x[b,ci,p]
//   demod[b,co] = rsqrt( sum_ci G[co,ci] * s[b,ci]^2 + 1e-8 ),  G = sum_t wsh^2
// ws layout (bytes):
//   xpad  bf16 [16][66][66][256] : 0          .. 35,684,352   (holds y, padded NHWC)
//   wsh   bf16 [9][256][256]     : 35,684,352 .. 36,864,000
//   s     f32  [16][256]         : 36,864,000 .. 36,880,384
//   G     f32  [256][256]        : 36,880,384 .. 37,142,528
//   demod f32  [16][256]         : 37,142,528 .. 37,158,912

#define WSH_OFF    35684352
#define S_OFF      36864000
#define G_OFF      36880384
#define DEMOD_OFF  37142528

typedef __attribute__((ext_vector_type(8))) short bf16x8;
typedef __attribute__((ext_vector_type(4))) float f32x4;
typedef __attribute__((ext_vector_type(4))) int i32x4;

#define GLOAD_LDS16(g, l)                                                        \
  __builtin_amdgcn_global_load_lds(                                              \
      (const __attribute__((address_space(1))) void*)(g),                        \
      (__attribute__((address_space(3))) void*)(l), 16, 0, 0)

__device__ __forceinline__ unsigned short f2bf(float f) {
  unsigned int u = __builtin_bit_cast(unsigned int, f);
  u += 0x7FFFu + ((u >> 16) & 1u);  // round-to-nearest-even
  return (unsigned short)(u >> 16);
}

// ---------------- kernel 1: style s[b][i]  +  shared weights & G ----------------
// blocks 0..15: style GEMV. blocks 16..271: wsh + G.
__global__ void prep1_k(const float* __restrict__ c_trg,
                        const float* __restrict__ style_w,
                        const float* __restrict__ style_b,
                        const float* __restrict__ weight,
                        float* __restrict__ s,
                        short* __restrict__ wsh,
                        float* __restrict__ G) {
  const int blk = blockIdx.x;
  const int tid = threadIdx.x;
  if (blk < 16) {
    const int b = blk;
    const float* ct = c_trg + b * 128;
    const float* sw = style_w + tid * 128;
    float acc = 0.f;
#pragma unroll 4
    for (int d = 0; d < 128; ++d) acc += ct[d] * sw[d];
    s[b * 256 + tid] = acc * 0.08838834764831845f + style_b[tid];  // 1/sqrt(128)
  } else {
    const int idx = (blk - 16) * 256 + tid;  // co*256+ci
    const float* wsrc = weight + idx * 9;    // 9 contiguous taps
    float g = 0.f;
#pragma unroll
    for (int t = 0; t < 9; ++t) {
      float v = wsrc[t] * 0.020833333333333332f;  // 1/sqrt(2304)
      g += v * v;
      wsh[t * 65536 + idx] = (short)f2bf(v);
    }
    G[idx] = g;
  }
}

// ---------------- kernel 2: demod[b][co] ----------------
__global__ void demod_k(const float* __restrict__ G,
                        const float* __restrict__ s,
                        float* __restrict__ demod) {
  const int bid = blockIdx.x;  // b*256 + co
  const int b = bid >> 8, co = bid & 255;
  const int t = threadIdx.x;
  const float sv = s[b * 256 + t];
  float ss = G[co * 256 + t] * sv * sv;
#pragma unroll
  for (int o = 32; o; o >>= 1) ss += __shfl_down(ss, o);
  __shared__ float red[4];
  if ((t & 63) == 0) red[t >> 6] = ss;
  __syncthreads();
  if (t == 0) demod[bid] = rsqrtf(red[0] + red[1] + red[2] + red[3] + 1e-8f);
}

// ---------------- kernel 3: y = s*x, fp32 NCHW -> bf16 padded NHWC; + border zero ----
// blocks 0..4095: transpose 64c x 64w tile via LDS. blocks 4096..4111: zero borders.
__global__ void xpose_k(const float* __restrict__ x,
                        const float* __restrict__ s,
                        short* __restrict__ xpad) {
  __shared__ float tile[64][65];
  const int bid = blockIdx.x;
  const int tid = threadIdx.x;
  if (bid >= 4096) {
    // zero the padding border of sample b: rows h=0,65 + cols w=0,65
    const int b = bid - 4096;
    char* base = (char*)xpad + b * 66 * 66 * 512;
    const i32x4 z = {0, 0, 0, 0};
    // rows h=0 and h=65: 66*512 = 33792 B each -> 2112 16B-stores each
    for (int i = tid; i < 4224; i += 256) {
      const int r = i >= 2112;
      const int off = r * (65 * 66 * 512) + (i - r * 2112) * 16;
      *(i32x4*)(base + off) = z;
    }
    // cols w=0 and w=65 for h=1..64: 512 B each
    for (int i = tid; i < 4096; i += 256) {
      const int h = 1 + (i >> 6);
      const int side = (i >> 5) & 1;
      const int j = i & 31;
      *(i32x4*)(base + (h * 66 + side * 65) * 512 + j * 16) = z;
    }
    return;
  }
  const int ct = bid & 3;
  const int h = (bid >> 2) & 63;
  const int b = bid >> 8;
  const int w = tid & 63, cl = tid >> 6;
  const float* src = x + ((b * 256 + ct * 64) * 64 + h) * 64;
#pragma unroll
  for (int i = 0; i < 16; ++i) {
    int c = i * 4 + cl;
    tile[c][w] = src[c * 4096 + w];
  }
  // style scale for this thread's channel pair (cp = tid&31, i-independent)
  const int cp = tid & 31;
  const float s0 = s[b * 256 + ct * 64 + cp * 2];
  const float s1 = s[b * 256 + ct * 64 + cp * 2 + 1];
  __syncthreads();
  short* dst = xpad + ((b * 66 + h + 1) * 66 + 1) * 256 + ct * 64;
#pragma unroll
  for (int i = 0; i < 8; ++i) {
    int idx = i * 256 + tid;
    int w2 = idx >> 5;  // 0..63
    unsigned int u = (unsigned int)f2bf(tile[cp * 2][w2] * s0) |
                     ((unsigned int)f2bf(tile[cp * 2 + 1][w2] * s1) << 16);
    *(unsigned int*)(dst + w2 * 256 + cp * 2) = u;
  }
}

// ---------------- kernel 4: implicit-GEMM conv, 128x128 tile, BK=64 ----------------
// grid: 16 samples * 2 cout-tiles * 32 pixel-tiles(2 rows). 256 thr = 4 waves.
// T1: bijective XCD swizzle -> each XCD owns 2 samples (L2-resident working set).
// T2: LDS XOR-swizzle (byte ^= (row&7)<<4) via pre-swizzled GLOBAL source
//     (global_load_lds writes linearly), swizzled ds_read addresses.
// A-operand (wsh) is batch-independent: 1.18 MB, L2-resident on every XCD.
__global__ __launch_bounds__(256) void conv_k(const short* __restrict__ xpad,
                                              const short* __restrict__ wsh,
                                              const float* __restrict__ demod,
                                              float* __restrict__ out) {
  __shared__ __align__(16) short As[128 * 64];  // [cout 128][cin 64]
  __shared__ __align__(16) short Bs[128 * 64];  // [pixel 128][cin 64]

  const int tid = threadIdx.x;
  const int lane = tid & 63;
  const int wid = tid >> 6;
  const int wr = wid >> 1, wc = wid & 1;

  // T1: XCD-aware swizzle. grid=1024, 1024%8==0 -> simple bijective form.
  const int orig = blockIdx.x;
  const int bid = (orig & 7) * 128 + (orig >> 3);

  const int b = bid >> 6;
  const int rem = bid & 63;
  const int cout0 = (rem & 1) * 128;
  const int r0 = (rem >> 1) * 2;  // first output row of this tile

  // staging address precompute: chunk q = i*256+tid; row=q>>3; 16B col = (tid&7)*16
  const int t3 = tid >> 3;
  const int c16 = (tid & 7) * 16;
  // T2 write side: LDS slot (row, c16) receives global (row, c16 ^ ((row&7)<<4)).
  const int swzc = c16 ^ ((t3 & 7) << 4);
  int aRow[4], bPix[4];
#pragma unroll
  for (int i = 0; i < 4; ++i) {
    aRow[i] = (cout0 + i * 32 + t3) * 512 + swzc;  // bytes into wsh[tap]
    int n = i * 32 + t3;                           // pixel 0..127
    int h = r0 + (n >> 6), w = n & 63;
    bPix[i] = ((b * 66 + h) * 66 + w) * 512 + swzc;  // bytes into xpad
  }

  const char* wB = (const char*)wsh;
  const char* xB = (const char*)xpad;

  f32x4 acc[4][4] = {};

  // T2 read side: col_read = col ^ ((row&7)<<4); row&7 == lane&7 for all m,ks.
  const int xall = (lane & 7) << 4;
  const int xl = xall & 0x30;
  const int xh = xall & 0x40;
  const int colR = (((lane >> 4) << 4) ^ xl);
  const int ksOff0 = xh;
  const int ksOff1 = 64 ^ xh;
  const char* Ard = (const char*)As + (wr * 64 + (lane & 15)) * 128 + colR;
  const char* Brd = (const char*)Bs + (wc * 64 + (lane & 15)) * 128 + colR;

  for (int tap = 0; tap < 9; ++tap) {
    const int aTap = tap * 131072;                        // bytes into wsh
    const int bTap = ((tap / 3) * 66 + (tap % 3)) * 512;  // row/col shift
#pragma unroll 1
    for (int cc = 0; cc < 4; ++cc) {
      const int ccB = cc * 128;
#pragma unroll
      for (int i = 0; i < 4; ++i) {
        GLOAD_LDS16(wB + aTap + aRow[i] + ccB, (char*)As + (i * 4 + wid) * 1024);
        GLOAD_LDS16(xB + bTap + bPix[i] + ccB, (char*)Bs + (i * 4 + wid) * 1024);
      }
      __syncthreads();
#pragma unroll
      for (int ks = 0; ks < 2; ++ks) {
        const int ko = ks ? ksOff1 : ksOff0;
        bf16x8 af[4], bfr[4];
#pragma unroll
        for (int m = 0; m < 4; ++m) af[m] = *(const bf16x8*)(Ard + m * 2048 + ko);
#pragma unroll
        for (int n = 0; n < 4; ++n) bfr[n] = *(const bf16x8*)(Brd + n * 2048 + ko);
#pragma unroll
        for (int m = 0; m < 4; ++m)
#pragma unroll
          for (int n = 0; n < 4; ++n)
            acc[m][n] = __builtin_amdgcn_mfma_f32_16x16x32_bf16(af[m], bfr[n], acc[m][n], 0, 0, 0);
      }
      __syncthreads();
    }
  }

  // epilogue: scale by demod[b][cout], store fp32 NCHW
  const int pc = lane & 15;
  const int rOff = (lane >> 4) * 4;
#pragma unroll
  for (int m = 0; m < 4; ++m) {
#pragma unroll
    for (int r = 0; r < 4; ++r) {
      const int co = cout0 + wr * 64 + m * 16 + rOff + r;
      const float dm = demod[(b << 8) + co];
      float* orow = out + (((b << 8) + co) << 12);
#pragma unroll
      for (int n = 0; n < 4; ++n) {
        const int pix = wc * 64 + n * 16 + pc;
        const int h = r0 + (pix >> 6), w = pix & 63;
        orow[(h << 6) + w] = acc[m][n][r] * dm;
      }
    }
  }
}

// ---------------- launcher ----------------
extern "C" void kernel_launch(void* const* d_in, const int* in_sizes, int n_in,
                              void* d_out, int out_size, void* d_ws, size_t ws_size,
                              hipStream_t stream) {
  const float* x       = (const float*)d_in[0];
  // d_in[1] = c_src (unused by reference)
  const float* c_trg   = (const float*)d_in[2];
  const float* style_w = (const float*)d_in[3];
  const float* style_b = (const float*)d_in[4];
  const float* weight  = (const float*)d_in[5];
  float* out = (float*)d_out;

  char* ws = (char*)d_ws;
  short* xpad  = (short*)(ws);
  short* wsh   = (short*)(ws + WSH_OFF);
  float* s     = (float*)(ws + S_OFF);
  float* G     = (float*)(ws + G_OFF);
  float* demod = (float*)(ws + DEMOD_OFF);

  prep1_k<<<272, 256, 0, stream>>>(c_trg, style_w, style_b, weight, s, wsh, G);
  demod_k<<<4096, 256, 0, stream>>>(G, s, demod);
  xpose_k<<<4112, 256, 0, stream>>>(x, s, xpad);
  conv_k<<<1024, 256, 0, stream>>>(xpad, wsh, demod, out);
}

// Round 4
// 106.817 us; speedup vs baseline: 1.5868x; 1.1337x over previous
//
#include <hip/hip_runtime.h>

// ---------------- constants ----------------
// B=16, CIN=256, COUT=256, H=W=64, K=3, SDIM=128
// Separable reformulation:
//   out[b,co,p] = demod[b,co] * sum_{t,ci} wsh[t,co,ci] * y[b,ci,p+shift(t)]
//   wsh = conv_scale * w  (batch-independent!),  y = s[b,ci] * x[b,ci,p]
//   demod[b,co] = rsqrt( sum_ci G[co,ci] * s[b,ci]^2 + 1e-8 ),  G = sum_t wsh^2
// ws layout (bytes):
//   xpad  bf16 [16][66][66][256] : 0          .. 35,684,352   (holds y, padded NHWC)
//   wsh   bf16 [9][256][256]     : 35,684,352 .. 36,864,000
//   s     f32  [16][256]         : 36,864,000 .. 36,880,384
//   G     f32  [256][256]        : 36,880,384 .. 37,142,528
//   demod f32  [16][256]         : 37,142,528 .. 37,158,912

#define WSH_OFF    35684352
#define S_OFF      36864000
#define G_OFF      36880384
#define DEMOD_OFF  37142528

typedef __attribute__((ext_vector_type(8))) short bf16x8;
typedef __attribute__((ext_vector_type(4))) float f32x4;
typedef __attribute__((ext_vector_type(4))) int i32x4;

#define GLOAD_LDS16(g, l)                                                        \
  __builtin_amdgcn_global_load_lds(                                              \
      (const __attribute__((address_space(1))) void*)(g),                        \
      (__attribute__((address_space(3))) void*)(l), 16, 0, 0)

__device__ __forceinline__ unsigned short f2bf(float f) {
  unsigned int u = __builtin_bit_cast(unsigned int, f);
  u += 0x7FFFu + ((u >> 16) & 1u);  // round-to-nearest-even
  return (unsigned short)(u >> 16);
}

// ---------------- kernel 1: style s[b][i]  +  shared weights & G ----------------
// blocks 0..15: style GEMV. blocks 16..271: wsh + G.
__global__ void prep1_k(const float* __restrict__ c_trg,
                        const float* __restrict__ style_w,
                        const float* __restrict__ style_b,
                        const float* __restrict__ weight,
                        float* __restrict__ s,
                        short* __restrict__ wsh,
                        float* __restrict__ G) {
  const int blk = blockIdx.x;
  const int tid = threadIdx.x;
  if (blk < 16) {
    const int b = blk;
    const float* ct = c_trg + b * 128;
    const float* sw = style_w + tid * 128;
    float acc = 0.f;
#pragma unroll 4
    for (int d = 0; d < 128; ++d) acc += ct[d] * sw[d];
    s[b * 256 + tid] = acc * 0.08838834764831845f + style_b[tid];  // 1/sqrt(128)
  } else {
    const int idx = (blk - 16) * 256 + tid;  // co*256+ci
    const float* wsrc = weight + idx * 9;    // 9 contiguous taps
    float g = 0.f;
#pragma unroll
    for (int t = 0; t < 9; ++t) {
      float v = wsrc[t] * 0.020833333333333332f;  // 1/sqrt(2304)
      g += v * v;
      wsh[t * 65536 + idx] = (short)f2bf(v);
    }
    G[idx] = g;
  }
}

// ---------------- kernel 2: demod[b][co] ----------------
__global__ void demod_k(const float* __restrict__ G,
                        const float* __restrict__ s,
                        float* __restrict__ demod) {
  const int bid = blockIdx.x;  // b*256 + co
  const int b = bid >> 8, co = bid & 255;
  const int t = threadIdx.x;
  const float sv = s[b * 256 + t];
  float ss = G[co * 256 + t] * sv * sv;
#pragma unroll
  for (int o = 32; o; o >>= 1) ss += __shfl_down(ss, o);
  __shared__ float red[4];
  if ((t & 63) == 0) red[t >> 6] = ss;
  __syncthreads();
  if (t == 0) demod[bid] = rsqrtf(red[0] + red[1] + red[2] + red[3] + 1e-8f);
}

// ---------------- kernel 3: y = s*x, fp32 NCHW -> bf16 padded NHWC; + border zero ----
// blocks 0..4095: transpose 64c x 64w tile via LDS. blocks 4096..4111: zero borders.
__global__ void xpose_k(const float* __restrict__ x,
                        const float* __restrict__ s,
                        short* __restrict__ xpad) {
  __shared__ float tile[64][65];
  const int bid = blockIdx.x;
  const int tid = threadIdx.x;
  if (bid >= 4096) {
    // zero the padding border of sample b: rows h=0,65 + cols w=0,65
    const int b = bid - 4096;
    char* base = (char*)xpad + b * 66 * 66 * 512;
    const i32x4 z = {0, 0, 0, 0};
    for (int i = tid; i < 4224; i += 256) {
      const int r = i >= 2112;
      const int off = r * (65 * 66 * 512) + (i - r * 2112) * 16;
      *(i32x4*)(base + off) = z;
    }
    for (int i = tid; i < 4096; i += 256) {
      const int h = 1 + (i >> 6);
      const int side = (i >> 5) & 1;
      const int j = i & 31;
      *(i32x4*)(base + (h * 66 + side * 65) * 512 + j * 16) = z;
    }
    return;
  }
  const int ct = bid & 3;
  const int h = (bid >> 2) & 63;
  const int b = bid >> 8;
  const int w = tid & 63, cl = tid >> 6;
  const float* src = x + ((b * 256 + ct * 64) * 64 + h) * 64;
#pragma unroll
  for (int i = 0; i < 16; ++i) {
    int c = i * 4 + cl;
    tile[c][w] = src[c * 4096 + w];
  }
  const int cp = tid & 31;
  const float s0 = s[b * 256 + ct * 64 + cp * 2];
  const float s1 = s[b * 256 + ct * 64 + cp * 2 + 1];
  __syncthreads();
  short* dst = xpad + ((b * 66 + h + 1) * 66 + 1) * 256 + ct * 64;
#pragma unroll
  for (int i = 0; i < 8; ++i) {
    int idx = i * 256 + tid;
    int w2 = idx >> 5;  // 0..63
    unsigned int u = (unsigned int)f2bf(tile[cp * 2][w2] * s0) |
                     ((unsigned int)f2bf(tile[cp * 2 + 1][w2] * s1) << 16);
    *(unsigned int*)(dst + w2 * 256 + cp * 2) = u;
  }
}

// ---------------- kernel 4: implicit-GEMM conv, 256x256 tile, BK=64 ----------------
// 512 thr = 8 waves (2 M x 4 N). LDS 128 KiB: 2 dbuf x (A 32KB + B 32KB).
// Counted-vmcnt double-buffer pipeline (T3/T4 mechanism):
//   prologue: stage tiles 0 (dbuf0), 1 (dbuf1)            [8 loads/thread each]
//   iter kk:  vmcnt(8)  -> tile kk retired, kk+1 in flight
//             barrier; ds_read + 64 MFMA/wave (setprio);  lgkmcnt(0); barrier
//             stage tile kk+2 into dbuf kk&1  (region free: all reads done)
// T1: XCD swizzle (grid 256 % 8 == 0) -> 2 samples per XCD L2.
// T2: XOR swizzle byte ^= ((row&7)<<4), pre-swizzled global source + swizzled read.
__global__ __launch_bounds__(512, 2) void conv_k(const short* __restrict__ xpad,
                                                 const short* __restrict__ wsh,
                                                 const float* __restrict__ demod,
                                                 float* __restrict__ out) {
  extern __shared__ __align__(16) char lds[];  // 131072 B

  const int tid = threadIdx.x;
  const int lane = tid & 63;
  const int wid = tid >> 6;
  const int wm = wid >> 2;   // 0..1 : cout half
  const int wn = wid & 3;    // 0..3 : pixel quarter (output row r0+wn)

  // T1: XCD swizzle, grid=256
  const int orig = blockIdx.x;
  const int bid = (orig & 7) * 32 + (orig >> 3);
  const int b = bid >> 4;
  const int r0 = (bid & 15) * 4;  // 4 output rows per block

  // staging: per tile, 4 A-loads + 4 B-loads per thread (16 B each).
  // load i covers LDS rows i*64 + t3 (t3 = tid>>3), byte col (tid&7)*16.
  const int t3 = tid >> 3;
  const int c16 = (tid & 7) * 16;
  const int swzc = c16 ^ ((t3 & 7) << 4);  // T2 write side (row&7 == t3&7)
  int aBase[4], bBase[4];
#pragma unroll
  for (int i = 0; i < 4; ++i) {
    aBase[i] = (i * 64 + t3) * 512 + swzc;                     // bytes into wsh[tap]
    bBase[i] = ((b * 66 + r0 + i) * 66 + t3) * 512 + swzc;     // bytes into xpad
  }
  const char* wB = (const char*)wsh;
  const char* xB = (const char*)xpad;

  auto stage = [&](int kk, int d) {
    const int tap = kk >> 2, cc = kk & 3;
    const int dh = (tap * 11) >> 5;      // tap/3 for tap<=8
    const int dw = tap - dh * 3;
    const int aO = tap * 131072 + cc * 128;
    const int bO = (dh * 66 + dw) * 512 + cc * 128;
    char* ldsT = lds + d * 65536;
#pragma unroll
    for (int i = 0; i < 4; ++i)
      GLOAD_LDS16(wB + aO + aBase[i], ldsT + (i * 512 + tid) * 16);
#pragma unroll
    for (int i = 0; i < 4; ++i)
      GLOAD_LDS16(xB + bO + bBase[i], ldsT + 32768 + (i * 512 + tid) * 16);
  };

  // T2 read side: col_read = col ^ ((row&7)<<4); row&7 == lane&7 everywhere.
  const int xall = (lane & 7) << 4;
  const int xl = xall & 0x30;
  const int xh = xall & 0x40;
  const int colR = (((lane >> 4) << 4) ^ xl);
  const int ksOff0 = xh;
  const int ksOff1 = 64 ^ xh;
  const int aRd = (wm * 128 + (lane & 15)) * 128 + colR;           // A region
  const int bRd = 32768 + (wn * 64 + (lane & 15)) * 128 + colR;    // B region

  f32x4 acc[8][4] = {};

  stage(0, 0);
  stage(1, 1);

  for (int kk = 0; kk < 36; ++kk) {
    if (kk == 35) {
      asm volatile("s_waitcnt vmcnt(0)" ::: "memory");
    } else {
      asm volatile("s_waitcnt vmcnt(8)" ::: "memory");
    }
    __builtin_amdgcn_s_barrier();
    __builtin_amdgcn_sched_barrier(0);

    const char* Ab = lds + (kk & 1) * 65536 + aRd;
    const char* Bb = lds + (kk & 1) * 65536 + bRd;
#pragma unroll
    for (int ks = 0; ks < 2; ++ks) {
      const int ko = ks ? ksOff1 : ksOff0;
      bf16x8 af[8], bfr[4];
#pragma unroll
      for (int m = 0; m < 8; ++m) af[m] = *(const bf16x8*)(Ab + m * 2048 + ko);
#pragma unroll
      for (int n = 0; n < 4; ++n) bfr[n] = *(const bf16x8*)(Bb + n * 2048 + ko);
      __builtin_amdgcn_s_setprio(1);
#pragma unroll
      for (int m = 0; m < 8; ++m)
#pragma unroll
        for (int n = 0; n < 4; ++n)
          acc[m][n] = __builtin_amdgcn_mfma_f32_16x16x32_bf16(af[m], bfr[n], acc[m][n], 0, 0, 0);
      __builtin_amdgcn_s_setprio(0);
    }

    asm volatile("s_waitcnt lgkmcnt(0)" ::: "memory");
    __builtin_amdgcn_s_barrier();
    __builtin_amdgcn_sched_barrier(0);
    asm volatile("" ::: "memory");
    if (kk + 2 < 36) stage(kk + 2, kk & 1);
  }

  // epilogue: scale by demod[b][cout], store fp32 NCHW.
  // wave (wm,wn): couts wm*128..+128, output row h=r0+wn, w = n*16 + pc.
  const int pc = lane & 15;
  const int rOff = (lane >> 4) * 4;
  const int h = r0 + wn;
#pragma unroll
  for (int m = 0; m < 8; ++m) {
#pragma unroll
    for (int r = 0; r < 4; ++r) {
      const int co = wm * 128 + m * 16 + rOff + r;
      const float dm = demod[(b << 8) + co];
      float* orow = out + (((b << 8) + co) << 12) + (h << 6);
#pragma unroll
      for (int n = 0; n < 4; ++n) {
        orow[n * 16 + pc] = acc[m][n][r] * dm;
      }
    }
  }
}

// ---------------- launcher ----------------
extern "C" void kernel_launch(void* const* d_in, const int* in_sizes, int n_in,
                              void* d_out, int out_size, void* d_ws, size_t ws_size,
                              hipStream_t stream) {
  const float* x       = (const float*)d_in[0];
  // d_in[1] = c_src (unused by reference)
  const float* c_trg   = (const float*)d_in[2];
  const float* style_w = (const float*)d_in[3];
  const float* style_b = (const float*)d_in[4];
  const float* weight  = (const float*)d_in[5];
  float* out = (float*)d_out;

  char* ws = (char*)d_ws;
  short* xpad  = (short*)(ws);
  short* wsh   = (short*)(ws + WSH_OFF);
  float* s     = (float*)(ws + S_OFF);
  float* G     = (float*)(ws + G_OFF);
  float* demod = (float*)(ws + DEMOD_OFF);

  hipFuncSetAttribute((const void*)conv_k,
                      hipFuncAttributeMaxDynamicSharedMemorySize, 131072);

  prep1_k<<<272, 256, 0, stream>>>(c_trg, style_w, style_b, weight, s, wsh, G);
  demod_k<<<4096, 256, 0, stream>>>(G, s, demod);
  xpose_k<<<4112, 256, 0, stream>>>(x, s, xpad);
  conv_k<<<256, 512, 131072, stream>>>(xpad, wsh, demod, out);
}